// Round 12
// baseline (284.093 us; speedup 1.0000x reference)
//
#include <hip/hip_runtime.h>

#define BB 4
#define SS 2048
#define DD 1024
#define HH 16
#define DH 64

typedef __attribute__((ext_vector_type(8))) short short8;
typedef __attribute__((ext_vector_type(4))) float floatx4;
typedef __attribute__((ext_vector_type(16))) float floatx16;
typedef __attribute__((ext_vector_type(2))) unsigned int uint2v;

static __device__ __forceinline__ float b2f(unsigned short u) {
  union { unsigned int i; float f; } c; c.i = ((unsigned int)u) << 16; return c.f;
}
static __device__ __forceinline__ unsigned short f2b(float f) {
  union { float ff; unsigned int i; } c; c.ff = f;
  unsigned int x = c.i;
  return (unsigned short)((x + 0x7fffu + ((x >> 16) & 1u)) >> 16);
}

#define MFMA16(a, b, c) __builtin_amdgcn_mfma_f32_16x16x32_bf16((a), (b), (c), 0, 0, 0)
#define MFMA32(a, b, c) __builtin_amdgcn_mfma_f32_32x32x16_bf16((a), (b), (c), 0, 0, 0)

// async global->LDS, 16 B per lane; LDS dest = wave-uniform base + lane*16
#define ASYNC16(g, l)                                                        \
  __builtin_amdgcn_global_load_lds(                                          \
      (const __attribute__((address_space(1))) unsigned int*)(g),            \
      (__attribute__((address_space(3))) unsigned int*)(l), 16, 0, 0)

// ---------------------------------------------------------------------------
// cvt_all: one-shot fp32 -> bf16 for x and the 4 weight matrices, PLUS
// interleaved {cos,sin} RoPE table (2048 pos x 32 j, float2) for the fused
// qkv epilogue (float2 halves the epilogue's table-load instruction count).
// ---------------------------------------------------------------------------
__global__ __launch_bounds__(256) void cvt_all(
    const float* __restrict__ x, const float* __restrict__ wq,
    const float* __restrict__ wk, const float* __restrict__ wv,
    const float* __restrict__ wo,
    unsigned short* __restrict__ x16, unsigned short* __restrict__ w16,
    unsigned short* __restrict__ wo16, float2* __restrict__ cstab) {
  const int blk = blockIdx.x;
  const int t = threadIdx.x;

  if (blk >= 6144) {                     // RoPE table gen: 256 blocks
    const int idx = ((blk - 6144) << 8) + t;        // 0..65535 = pos*32 + j
    const int j = idx & 31;
    const float pf = (float)(idx >> 5);
    const float ang = pf * exp2f(-0.41524101186091903f * (float)j);
    float sv, cv;
    sincosf(ang, &sv, &cv);
    cstab[idx] = make_float2(cv, sv);
    return;
  }

  const float* src;
  unsigned short* dst;
  size_t off;
  if (blk < 4096)      { src = x;  dst = x16;             off = (size_t)blk * 2048; }
  else if (blk < 4608) { src = wq; dst = w16;             off = (size_t)(blk - 4096) * 2048; }
  else if (blk < 5120) { src = wk; dst = w16 + (1 << 20); off = (size_t)(blk - 4608) * 2048; }
  else if (blk < 5632) { src = wv; dst = w16 + (2 << 20); off = (size_t)(blk - 5120) * 2048; }
  else                 { src = wo; dst = wo16;            off = (size_t)(blk - 5632) * 2048; }
  const float4* s4 = (const float4*)(src + off) + t * 2;
  const float4 a = s4[0], bq = s4[1];
  union { short8 v; unsigned short u[8]; } p;
  p.u[0] = f2b(a.x);  p.u[1] = f2b(a.y);  p.u[2] = f2b(a.z);  p.u[3] = f2b(a.w);
  p.u[4] = f2b(bq.x); p.u[5] = f2b(bq.y); p.u[6] = f2b(bq.z); p.u[7] = f2b(bq.w);
  *(short8*)(dst + off + (size_t)t * 8) = p.v;
}

// ---------------------------------------------------------------------------
// qkv_gemm v2 (round-9 structure): C[8192,3072] = x16@w16^T, bf16.  128x128
// tile, BK=64, XOR-swizzled LDS -> conflict-free ds_read_b128.  Epilogue:
// q,k RoPE-fused (float2 cos/sin table); v -> vt[B,H,DH,S].
// ---------------------------------------------------------------------------
__global__ __launch_bounds__(256) void qkv_gemm(
    const unsigned short* __restrict__ x16, const unsigned short* __restrict__ w16,
    const int* __restrict__ tpos, const float2* __restrict__ cstab,
    unsigned short* __restrict__ qb, unsigned short* __restrict__ kb,
    unsigned short* __restrict__ vt) {
  __shared__ __align__(16) unsigned short As[128 * 64];   // 16 KB
  __shared__ __align__(16) unsigned short Bs[128 * 64];   // 16 KB

  const int blk = blockIdx.x;           // 64 m-tiles (fast) x 24 n-tiles
  const int m0 = (blk & 63) * 128;
  const int nblk = blk >> 6;
  const int mat = nblk >> 3;
  const int c0 = (nblk & 7) * 128;

  const int tid = threadIdx.x;
  const int lane = tid & 63, wave = tid >> 6;
  const int wm = (wave >> 1) * 64, wn = (wave & 1) * 64;
  const int quad = lane >> 4, l15 = lane & 15;

  const int srw = lane >> 3;
  const int scw = ((lane & 7) ^ srw) * 8;
  const unsigned short* ag = x16 + (size_t)(m0 + wave * 32 + srw) * DD + scw;
  const unsigned short* bg = w16 + (size_t)(nblk * 128 + wave * 32 + srw) * DD + scw;
  unsigned short* al = &As[wave * 2048];
  unsigned short* bl = &Bs[wave * 2048];

  const int rx = l15 & 7;               // read-side XOR (row&7 == l15&7)

  floatx4 acc[4][4] = {};

  for (int k0 = 0; k0 < DD; k0 += 64) {
    ASYNC16(ag + k0,           al);
    ASYNC16(ag + 8 * DD + k0,  al + 512);
    ASYNC16(ag + 16 * DD + k0, al + 1024);
    ASYNC16(ag + 24 * DD + k0, al + 1536);
    ASYNC16(bg + k0,           bl);
    ASYNC16(bg + 8 * DD + k0,  bl + 512);
    ASYNC16(bg + 16 * DD + k0, bl + 1024);
    ASYNC16(bg + 24 * DD + k0, bl + 1536);
    __syncthreads();
#pragma unroll
    for (int ks = 0; ks < 2; ++ks) {
      short8 af[4], bf[4];
#pragma unroll
      for (int mt = 0; mt < 4; ++mt)
        af[mt] = *(const short8*)&As[(wm + mt * 16 + l15) * 64 +
                                     (((ks * 4 + quad) ^ rx) * 8)];
#pragma unroll
      for (int nt = 0; nt < 4; ++nt)
        bf[nt] = *(const short8*)&Bs[(wn + nt * 16 + l15) * 64 +
                                     (((ks * 4 + quad) ^ rx) * 8)];
#pragma unroll
      for (int mt = 0; mt < 4; ++mt)
#pragma unroll
        for (int nt = 0; nt < 4; ++nt)
          acc[mt][nt] = MFMA16(af[mt], bf[nt], acc[mt][nt]);
    }
    __syncthreads();
  }

  if (mat < 2) {
    // q/k epilogue with fused RoPE (float2 table: one 8B load per d-pair).
    unsigned short* dst = (mat == 0) ? qb : kb;
    const int odd = l15 & 1;
#pragma unroll
    for (int mt = 0; mt < 4; ++mt) {
#pragma unroll
      for (int r = 0; r < 4; ++r) {
        const int row = m0 + wm + mt * 16 + quad * 4 + r;
        const int pos = tpos[row];
        const float2* ct = cstab + (pos << 5);
        const int b = row >> 11, s = row & (SS - 1);
#pragma unroll
        for (int nt = 0; nt < 4; ++nt) {
          const int d = nt * 16 + l15;
          const float2 cs = ct[d >> 1];
          const float self = acc[mt][nt][r];
          const float partner = __shfl_xor(self, 1, 64);
          // even d: e*cos - o*sin ; odd d: e*sin + o*cos
          const float o = odd ? (partner * cs.y + self * cs.x)
                              : (self * cs.x - partner * cs.y);
          const int c = c0 + wn + d;
          const int h = c >> 6;
          dst[(((size_t)(b * HH + h)) * SS + s) * DH + d] = f2b(o);
        }
      }
    }
  } else {
#pragma unroll
    for (int mt = 0; mt < 4; ++mt) {
#pragma unroll
      for (int nt = 0; nt < 4; ++nt) {
        const int c = c0 + wn + nt * 16 + l15;
        const int h = c >> 6, d = c & 63;
        const int row0 = m0 + wm + mt * 16 + quad * 4;
        const int b = row0 >> 11, s0 = row0 & (SS - 1);
        union { unsigned short u[4]; uint2 v2; } pk;
#pragma unroll
        for (int r = 0; r < 4; ++r) pk.u[r] = f2b(acc[mt][nt][r]);
        *(uint2*)&vt[(((size_t)(b * HH + h)) * DH + d) * SS + s0] = pk.v2;
      }
    }
  }
}

// ---------------------------------------------------------------------------
// attn (round-11 structure; separate merge kernel, no device fences in hot
// kernels).  32x32x16 MFMA, 4 waves x 32 q-rows, KVBLK=64, swapped QK^T,
// in-register softmax (4-way lsum accumulators: 8-deep add chains instead of
// 32), permlane32_swap PV A-frags, XOR-swizzled K/V LDS via global_load_lds.
//   attn_flash - one block per q-tile (fallback when workspace is small)
//   attn_split - heavy q-tiles (qp>=8) split over 2 blocks along K; partials
//                bf16 pO + fp32 pL; merge adds in fp32.
// ---------------------------------------------------------------------------

// schedule table for attn_split: 24 entries, descending work.
// ORD[u] = qp*4 + mode, mode: 0 = split half 0, 1 = split half 1, 2 = light.
static __device__ const unsigned char ORD[24] = {
    60, 61, 30, 56, 57, 52, 53, 26, 48, 49, 44, 45,
    22, 40, 41, 36, 37, 18, 32, 33, 14, 10, 6, 2};

__global__ __launch_bounds__(256, 4) void attn_flash(
    const unsigned short* __restrict__ q, const unsigned short* __restrict__ k,
    const unsigned short* __restrict__ vt, unsigned short* __restrict__ ao) {
  const int blk = blockIdx.x;          // (15-qp)*64 + bh  (bh fastest)
  const int bh = blk & 63, qp = 15 - (blk >> 6);
  const int b = bh >> 4, h = bh & 15;
  const size_t kvbase = (size_t)bh * SS * DH;
  const size_t vtbase = (size_t)bh * DH * SS;

  const int tid = threadIdx.x;
  const int lane = tid & 63, wv = tid >> 6;
  const int l31 = lane & 31, hl = lane >> 5;

  __shared__ __align__(16) unsigned short Ks[2][64 * 64];
  __shared__ __align__(16) unsigned short Vs[2][64 * 64];

  int srowi[2], sgc[2];
#pragma unroll
  for (int c = 0; c < 2; ++c) {
    const int i16 = (wv * 2 + c) * 64 + lane;
    srowi[c] = i16 >> 3;
    sgc[c] = (i16 & 7) ^ (srowi[c] & 7);
  }

#define STAGE(bi, kt)                                                         \
  do {                                                                        \
    ASYNC16(k + kvbase + (size_t)((kt) * 64 + srowi[0]) * DH + sgc[0] * 8,    \
            &Ks[bi][(wv * 2 + 0) * 512]);                                     \
    ASYNC16(k + kvbase + (size_t)((kt) * 64 + srowi[1]) * DH + sgc[1] * 8,    \
            &Ks[bi][(wv * 2 + 1) * 512]);                                     \
    ASYNC16(vt + vtbase + (size_t)srowi[0] * SS + (kt) * 64 + sgc[0] * 8,     \
            &Vs[bi][(wv * 2 + 0) * 512]);                                     \
    ASYNC16(vt + vtbase + (size_t)srowi[1] * SS + (kt) * 64 + sgc[1] * 8,     \
            &Vs[bi][(wv * 2 + 1) * 512]);                                     \
  } while (0)

  const int Q0 = qp * 128;
  const int nt = 2 * qp + 2;
  const int ew = 2 * qp + (wv >> 1);
  const int qa = Q0 + wv * 32 + l31;

  short8 qf[4];
#pragma unroll
  for (int ks = 0; ks < 4; ++ks)
    qf[ks] = *(const short8*)(q + kvbase + (size_t)qa * DH + ks * 16 + hl * 8);

  floatx16 oacc[2] = {};
  float ls[4] = {0.f, 0.f, 0.f, 0.f};

  STAGE(0, 0);
  __syncthreads();

  for (int kt = 0; kt < nt; ++kt) {
    const int cur = kt & 1;
    if (kt + 1 < nt) STAGE((kt + 1) & 1, kt + 1);

    if (kt <= ew) {
      floatx16 st[2] = {};
      __builtin_amdgcn_s_setprio(1);
#pragma unroll
      for (int g = 0; g < 2; ++g) {
        const int row = g * 32 + l31;
        const int rx = row & 7;
#pragma unroll
        for (int ks = 0; ks < 4; ++ks) {
          const int u = row * 8 + ((ks * 2 + hl) ^ rx);
          short8 kf = *(const short8*)&Ks[cur][u * 8];
          st[g] = MFMA32(kf, qf[ks], st[g]);
        }
      }
      __builtin_amdgcn_s_setprio(0);

      float pv[2][16];
      if (kt == ew) {
#pragma unroll
        for (int g = 0; g < 2; ++g)
#pragma unroll
          for (int r = 0; r < 16; ++r) {
            const int key = kt * 64 + g * 32 + (r & 3) + 8 * (r >> 2) + 4 * hl;
            const float e = (key > qa)
                ? 0.f
                : exp2f(st[g][r] * 0.18033688011112042f - 11.541560327111707f);
            pv[g][r] = e;
            ls[(g << 1) | (r & 1)] += e;
          }
      } else {
#pragma unroll
        for (int g = 0; g < 2; ++g)
#pragma unroll
          for (int r = 0; r < 16; ++r) {
            const float e =
                exp2f(st[g][r] * 0.18033688011112042f - 11.541560327111707f);
            pv[g][r] = e;
            ls[(g << 1) | (r & 1)] += e;
          }
      }

      unsigned int W[2][4][2];
#pragma unroll
      for (int g = 0; g < 2; ++g)
#pragma unroll
        for (int bb = 0; bb < 4; ++bb)
#pragma unroll
          for (int w = 0; w < 2; ++w)
            asm("v_cvt_pk_bf16_f32 %0, %1, %2"
                : "=v"(W[g][bb][w])
                : "v"(pv[g][4 * bb + 2 * w]), "v"(pv[g][4 * bb + 2 * w + 1]));

#pragma unroll
      for (int ks = 0; ks < 4; ++ks) {
        const int g = ks >> 1, c2 = (ks & 1) * 2;
        const uint2v w0 = __builtin_amdgcn_permlane32_swap(
            W[g][c2][0], W[g][c2 + 1][0], false, false);
        const uint2v w1 = __builtin_amdgcn_permlane32_swap(
            W[g][c2][1], W[g][c2 + 1][1], false, false);
        union { unsigned int u[4]; short8 s; } pa;
        pa.u[0] = w0.x;
        pa.u[1] = w1.x;
        pa.u[2] = w0.y;
        pa.u[3] = w1.y;
        __builtin_amdgcn_s_setprio(1);
#pragma unroll
        for (int dg = 0; dg < 2; ++dg) {
          const int row = dg * 32 + l31;
          const int u = row * 8 + ((ks * 2 + hl) ^ (row & 7));
          short8 vf = *(const short8*)&Vs[cur][u * 8];
          oacc[dg] = MFMA32(pa.s, vf, oacc[dg]);
        }
        __builtin_amdgcn_s_setprio(0);
      }
    }
    __syncthreads();
  }

  const float lsum = (ls[0] + ls[1]) + (ls[2] + ls[3]);
  const float rs = lsum + __shfl_xor(lsum, 32, 64);
  const float linv = 1.0f / rs;
#pragma unroll
  for (int r = 0; r < 16; ++r) {
    const int ql = (r & 3) + 8 * (r >> 2) + 4 * hl;
    const float li = __shfl(linv, ql, 64);
    const int qabs = Q0 + wv * 32 + ql;
#pragma unroll
    for (int dg = 0; dg < 2; ++dg) {
      const int d = dg * 32 + l31;
      ao[((size_t)(b * SS + qabs)) * DD + h * DH + d] = f2b(oacc[dg][r] * li);
    }
  }
#undef STAGE
}

__global__ __launch_bounds__(256, 4) void attn_split(
    const unsigned short* __restrict__ q, const unsigned short* __restrict__ k,
    const unsigned short* __restrict__ vt, unsigned short* __restrict__ ao,
    unsigned short* __restrict__ pO, float* __restrict__ pL) {
  const int blk = blockIdx.x;              // u*64 + bh (bh fastest)
  const int bh = blk & 63, u = blk >> 6;
  const int ent = ORD[u];
  const int qp = ent >> 2, mode = ent & 3;
  const int b = bh >> 4, h = bh & 15;
  const size_t kvbase = (size_t)bh * SS * DH;
  const size_t vtbase = (size_t)bh * DH * SS;

  const int kb = (mode == 1) ? (qp + 1) : 0;
  const int ke = (mode == 0) ? (qp + 1) : (2 * qp + 2);

  const int tid = threadIdx.x;
  const int lane = tid & 63, wv = tid >> 6;
  const int l31 = lane & 31, hl = lane >> 5;

  __shared__ __align__(16) unsigned short Ks[2][64 * 64];
  __shared__ __align__(16) unsigned short Vs[2][64 * 64];

  int srowi[2], sgc[2];
#pragma unroll
  for (int c = 0; c < 2; ++c) {
    const int i16 = (wv * 2 + c) * 64 + lane;
    srowi[c] = i16 >> 3;
    sgc[c] = (i16 & 7) ^ (srowi[c] & 7);
  }

#define STAGE(bi, kt)                                                         \
  do {                                                                        \
    ASYNC16(k + kvbase + (size_t)((kt) * 64 + srowi[0]) * DH + sgc[0] * 8,    \
            &Ks[bi][(wv * 2 + 0) * 512]);                                     \
    ASYNC16(k + kvbase + (size_t)((kt) * 64 + srowi[1]) * DH + sgc[1] * 8,    \
            &Ks[bi][(wv * 2 + 1) * 512]);                                     \
    ASYNC16(vt + vtbase + (size_t)srowi[0] * SS + (kt) * 64 + sgc[0] * 8,     \
            &Vs[bi][(wv * 2 + 0) * 512]);                                     \
    ASYNC16(vt + vtbase + (size_t)srowi[1] * SS + (kt) * 64 + sgc[1] * 8,     \
            &Vs[bi][(wv * 2 + 1) * 512]);                                     \
  } while (0)

  const int Q0 = qp * 128;
  const int ew = 2 * qp + (wv >> 1);       // wave's edge tile (global index)
  const int qa = Q0 + wv * 32 + l31;

  short8 qf[4];
#pragma unroll
  for (int ks = 0; ks < 4; ++ks)
    qf[ks] = *(const short8*)(q + kvbase + (size_t)qa * DH + ks * 16 + hl * 8);

  floatx16 oacc[2] = {};
  float ls[4] = {0.f, 0.f, 0.f, 0.f};

  STAGE(0, kb);
  __syncthreads();

  for (int g0 = kb; g0 < ke; ++g0) {
    const int cur = (g0 - kb) & 1;
    if (g0 + 1 < ke) STAGE((g0 - kb + 1) & 1, g0 + 1);

    if (g0 <= ew) {
      floatx16 st[2] = {};
      __builtin_amdgcn_s_setprio(1);
#pragma unroll
      for (int g = 0; g < 2; ++g) {
        const int row = g * 32 + l31;
        const int rx = row & 7;
#pragma unroll
        for (int ks = 0; ks < 4; ++ks) {
          const int uu = row * 8 + ((ks * 2 + hl) ^ rx);
          short8 kf = *(const short8*)&Ks[cur][uu * 8];
          st[g] = MFMA32(kf, qf[ks], st[g]);
        }
      }
      __builtin_amdgcn_s_setprio(0);

      float pv[2][16];
      if (g0 == ew) {
#pragma unroll
        for (int g = 0; g < 2; ++g)
#pragma unroll
          for (int r = 0; r < 16; ++r) {
            const int key = g0 * 64 + g * 32 + (r & 3) + 8 * (r >> 2) + 4 * hl;
            const float e = (key > qa)
                ? 0.f
                : exp2f(st[g][r] * 0.18033688011112042f - 11.541560327111707f);
            pv[g][r] = e;
            ls[(g << 1) | (r & 1)] += e;
          }
      } else {
#pragma unroll
        for (int g = 0; g < 2; ++g)
#pragma unroll
          for (int r = 0; r < 16; ++r) {
            const float e =
                exp2f(st[g][r] * 0.18033688011112042f - 11.541560327111707f);
            pv[g][r] = e;
            ls[(g << 1) | (r & 1)] += e;
          }
      }

      unsigned int W[2][4][2];
#pragma unroll
      for (int g = 0; g < 2; ++g)
#pragma unroll
        for (int bb = 0; bb < 4; ++bb)
#pragma unroll
          for (int w = 0; w < 2; ++w)
            asm("v_cvt_pk_bf16_f32 %0, %1, %2"
                : "=v"(W[g][bb][w])
                : "v"(pv[g][4 * bb + 2 * w]), "v"(pv[g][4 * bb + 2 * w + 1]));

#pragma unroll
      for (int ks = 0; ks < 4; ++ks) {
        const int g = ks >> 1, c2 = (ks & 1) * 2;
        const uint2v w0 = __builtin_amdgcn_permlane32_swap(
            W[g][c2][0], W[g][c2 + 1][0], false, false);
        const uint2v w1 = __builtin_amdgcn_permlane32_swap(
            W[g][c2][1], W[g][c2 + 1][1], false, false);
        union { unsigned int uu[4]; short8 s; } pa;
        pa.uu[0] = w0.x;
        pa.uu[1] = w1.x;
        pa.uu[2] = w0.y;
        pa.uu[3] = w1.y;
        __builtin_amdgcn_s_setprio(1);
#pragma unroll
        for (int dg = 0; dg < 2; ++dg) {
          const int row = dg * 32 + l31;
          const int uu = row * 8 + ((ks * 2 + hl) ^ (row & 7));
          short8 vf = *(const short8*)&Vs[cur][uu * 8];
          oacc[dg] = MFMA32(pa.s, vf, oacc[dg]);
        }
        __builtin_amdgcn_s_setprio(0);
      }
    }
    __syncthreads();
  }

  const float lsum = (ls[0] + ls[1]) + (ls[2] + ls[3]);
  if (mode == 2) {
    const float rs = lsum + __shfl_xor(lsum, 32, 64);
    const float linv = 1.0f / rs;
#pragma unroll
    for (int r = 0; r < 16; ++r) {
      const int ql = (r & 3) + 8 * (r >> 2) + 4 * hl;
      const float li = __shfl(linv, ql, 64);
      const int qabs = Q0 + wv * 32 + ql;
#pragma unroll
      for (int dg = 0; dg < 2; ++dg) {
        const int d = dg * 32 + l31;
        ao[((size_t)(b * SS + qabs)) * DD + h * DH + d] = f2b(oacc[dg][r] * li);
      }
    }
  } else {
    // partial store: bf16 unnormalized pV sums + fp32 row-sum
    const int slab = ((qp - 8) * 2 + mode) * 64 + bh;
    const float rs = lsum + __shfl_xor(lsum, 32, 64);
    if (hl == 0) pL[slab * 128 + wv * 32 + l31] = rs;
#pragma unroll
    for (int r = 0; r < 16; ++r) {
      const int ql = (r & 3) + 8 * (r >> 2) + 4 * hl;
      const int row = wv * 32 + ql;
#pragma unroll
      for (int dg = 0; dg < 2; ++dg) {
        const int d = dg * 32 + l31;
        pO[((size_t)slab * 128 + row) * 64 + d] = f2b(oacc[dg][r]);
      }
    }
  }
#undef STAGE
}

// merge the two K-halves of each heavy q-tile: ao = (O0+O1)/(l0+l1)
__global__ __launch_bounds__(256) void attn_merge(
    const unsigned short* __restrict__ pO, const float* __restrict__ pL,
    unsigned short* __restrict__ ao) {
  const int flat = blockIdx.x * 256 + threadIdx.x;   // 0..131071
  const int row = flat >> 1, dh = (flat & 1) * 32;   // 65536 rows x 2 halves
  const int bh = row >> 10, p = (row >> 7) & 7, rl = row & 127;
  const int b = bh >> 4, h = bh & 15;
  const int qabs = 1024 + p * 128 + rl;              // qp = 8+p
  const int slab0 = (p * 2 + 0) * 64 + bh;
  const int slab1 = slab0 + 64;
  const float l = pL[slab0 * 128 + rl] + pL[slab1 * 128 + rl];
  const float inv = 1.0f / l;
  const unsigned short* o0 = &pO[((size_t)slab0 * 128 + rl) * 64 + dh];
  const unsigned short* o1 = &pO[((size_t)slab1 * 128 + rl) * 64 + dh];
  unsigned short* dst = &ao[((size_t)(b * SS + qabs)) * DD + h * DH + dh];
#pragma unroll
  for (int j = 0; j < 4; ++j) {
    union { short8 v; unsigned short u[8]; } a8, c8, pk;
    a8.v = *(const short8*)(o0 + 8 * j);
    c8.v = *(const short8*)(o1 + 8 * j);
#pragma unroll
    for (int e = 0; e < 8; ++e)
      pk.u[e] = f2b((b2f(a8.u[e]) + b2f(c8.u[e])) * inv);
    *(short8*)(dst + 8 * j) = pk.v;
  }
}

// ---------------------------------------------------------------------------
// o_gemm v2 (unchanged from round 9): out[8192,1024](fp32) = ab @ wo16^T
// (bf16).  BK=64 + XOR-swizzled LDS.
// ---------------------------------------------------------------------------
__global__ __launch_bounds__(256) void o_gemm(
    const unsigned short* __restrict__ a, const unsigned short* __restrict__ w16,
    float* __restrict__ out) {
  __shared__ __align__(16) unsigned short As[128 * 64];
  __shared__ __align__(16) unsigned short Bs[128 * 64];

  const int blk = blockIdx.x;          // 64 m x 8 n
  const int m0 = (blk >> 3) * 128;
  const int n0 = (blk & 7) * 128;

  const int tid = threadIdx.x;
  const int lane = tid & 63, wave = tid >> 6;
  const int wm = (wave >> 1) * 64, wn = (wave & 1) * 64;
  const int quad = lane >> 4, l15 = lane & 15;

  const int srw = lane >> 3;
  const int scw = ((lane & 7) ^ srw) * 8;
  const unsigned short* ag = a + (size_t)(m0 + wave * 32 + srw) * DD + scw;
  const unsigned short* bg = w16 + (size_t)(n0 + wave * 32 + srw) * DD + scw;
  unsigned short* al = &As[wave * 2048];
  unsigned short* bl = &Bs[wave * 2048];

  const int rx = l15 & 7;

  floatx4 acc[4][4] = {};

  for (int k0 = 0; k0 < DD; k0 += 64) {
    ASYNC16(ag + k0,           al);
    ASYNC16(ag + 8 * DD + k0,  al + 512);
    ASYNC16(ag + 16 * DD + k0, al + 1024);
    ASYNC16(ag + 24 * DD + k0, al + 1536);
    ASYNC16(bg + k0,           bl);
    ASYNC16(bg + 8 * DD + k0,  bl + 512);
    ASYNC16(bg + 16 * DD + k0, bl + 1024);
    ASYNC16(bg + 24 * DD + k0, bl + 1536);
    __syncthreads();
#pragma unroll
    for (int ks = 0; ks < 2; ++ks) {
      short8 af[4], bf[4];
#pragma unroll
      for (int mt = 0; mt < 4; ++mt)
        af[mt] = *(const short8*)&As[(wm + mt * 16 + l15) * 64 +
                                     (((ks * 4 + quad) ^ rx) * 8)];
#pragma unroll
      for (int nt = 0; nt < 4; ++nt)
        bf[nt] = *(const short8*)&Bs[(wn + nt * 16 + l15) * 64 +
                                     (((ks * 4 + quad) ^ rx) * 8)];
#pragma unroll
      for (int mt = 0; mt < 4; ++mt)
#pragma unroll
        for (int nt = 0; nt < 4; ++nt)
          acc[mt][nt] = MFMA16(af[mt], bf[nt], acc[mt][nt]);
    }
    __syncthreads();
  }

#pragma unroll
  for (int mt = 0; mt < 4; ++mt) {
#pragma unroll
    for (int nt = 0; nt < 4; ++nt) {
#pragma unroll
      for (int r = 0; r < 4; ++r) {
        const int row = m0 + wm + mt * 16 + quad * 4 + r;
        const int col = n0 + wn + nt * 16 + l15;
        out[(size_t)row * DD + col] = acc[mt][nt][r];
      }
    }
  }
}

extern "C" void kernel_launch(void* const* d_in, const int* in_sizes, int n_in,
                              void* d_out, int out_size, void* d_ws, size_t ws_size,
                              hipStream_t stream) {
  const float* x  = (const float*)d_in[0];
  const int* tpos = (const int*)d_in[1];
  const float* wq = (const float*)d_in[2];
  const float* wk = (const float*)d_in[3];
  const float* wv = (const float*)d_in[4];
  const float* wo = (const float*)d_in[5];

  const size_t N = (size_t)BB * SS * DD;           // 8,388,608
  unsigned short* qb  = (unsigned short*)d_out;    // bf16 q [B,H,S,DH]   (16.8 MB)
  unsigned short* w16 = qb + N;                    // bf16 q|k|v weights  (6.3 MB)
  float2* cstab = (float2*)(w16 + (3u << 20));     // 2048x32 {cos,sin}   (512 KB)
  unsigned short* kb   = (unsigned short*)d_ws;    // bf16 k [B,H,S,DH]
  unsigned short* vb   = kb + N;                   // bf16 v^T [B,H,DH,S]
  unsigned short* ab   = vb + N;                   // bf16 attn [B,S,D]
  unsigned short* wo16 = ab + N;                   // bf16 wo
  unsigned short* x16  = ab;                       // alias: dead before attn writes ab
  float* out = (float*)d_out;

  // split-K attention partials (bf16 pO + fp32 pL), after wo16.
  const size_t base = (3 * N + (1u << 20)) * sizeof(unsigned short); // 52.43 MB
  const size_t WS_NEED = base + 8388608ull * sizeof(unsigned short)
                              + 131072ull * sizeof(float);

  cvt_all<<<6400, 256, 0, stream>>>(x, wq, wk, wv, wo, x16, w16, wo16, cstab);
  qkv_gemm<<<64 * 24, 256, 0, stream>>>(x16, w16, tpos, cstab, qb, kb, vb);
  if (ws_size >= WS_NEED) {
    unsigned short* pO = (unsigned short*)((char*)d_ws + base);
    float* pL = (float*)(pO + 8388608);
    attn_split<<<24 * 64, 256, 0, stream>>>(qb, kb, vb, ab, pO, pL);
    attn_merge<<<512, 256, 0, stream>>>(pO, pL, ab);
  } else {
    attn_flash<<<16 * 64, 256, 0, stream>>>(qb, kb, vb, ab);
  }
  o_gemm<<<64 * 8, 256, 0, stream>>>(ab, wo16, out);
}

// Round 13
// 266.963 us; speedup vs baseline: 1.0642x; 1.0642x over previous
//
#include <hip/hip_runtime.h>

#define BB 4
#define SS 2048
#define DD 1024
#define HH 16
#define DH 64

typedef __attribute__((ext_vector_type(8))) short short8;
typedef __attribute__((ext_vector_type(4))) float floatx4;
typedef __attribute__((ext_vector_type(16))) float floatx16;
typedef __attribute__((ext_vector_type(2))) unsigned int uint2v;

static __device__ __forceinline__ float b2f(unsigned short u) {
  union { unsigned int i; float f; } c; c.i = ((unsigned int)u) << 16; return c.f;
}
static __device__ __forceinline__ unsigned short f2b(float f) {
  union { float ff; unsigned int i; } c; c.ff = f;
  unsigned int x = c.i;
  return (unsigned short)((x + 0x7fffu + ((x >> 16) & 1u)) >> 16);
}

#define MFMA16(a, b, c) __builtin_amdgcn_mfma_f32_16x16x32_bf16((a), (b), (c), 0, 0, 0)
#define MFMA32(a, b, c) __builtin_amdgcn_mfma_f32_32x32x16_bf16((a), (b), (c), 0, 0, 0)

// async global->LDS, 16 B per lane; LDS dest = wave-uniform base + lane*16
#define ASYNC16(g, l)                                                        \
  __builtin_amdgcn_global_load_lds(                                          \
      (const __attribute__((address_space(1))) unsigned int*)(g),            \
      (__attribute__((address_space(3))) unsigned int*)(l), 16, 0, 0)

// ---------------------------------------------------------------------------
// cvt_all: one-shot fp32 -> bf16 for x and the 4 weight matrices, PLUS
// interleaved {cos,sin} RoPE table (2048 pos x 32 j, float2) for the fused
// qkv epilogue.
// ---------------------------------------------------------------------------
__global__ __launch_bounds__(256) void cvt_all(
    const float* __restrict__ x, const float* __restrict__ wq,
    const float* __restrict__ wk, const float* __restrict__ wv,
    const float* __restrict__ wo,
    unsigned short* __restrict__ x16, unsigned short* __restrict__ w16,
    unsigned short* __restrict__ wo16, float2* __restrict__ cstab) {
  const int blk = blockIdx.x;
  const int t = threadIdx.x;

  if (blk >= 6144) {                     // RoPE table gen: 256 blocks
    const int idx = ((blk - 6144) << 8) + t;        // 0..65535 = pos*32 + j
    const int j = idx & 31;
    const float pf = (float)(idx >> 5);
    const float ang = pf * exp2f(-0.41524101186091903f * (float)j);
    float sv, cv;
    sincosf(ang, &sv, &cv);
    cstab[idx] = make_float2(cv, sv);
    return;
  }

  const float* src;
  unsigned short* dst;
  size_t off;
  if (blk < 4096)      { src = x;  dst = x16;             off = (size_t)blk * 2048; }
  else if (blk < 4608) { src = wq; dst = w16;             off = (size_t)(blk - 4096) * 2048; }
  else if (blk < 5120) { src = wk; dst = w16 + (1 << 20); off = (size_t)(blk - 4608) * 2048; }
  else if (blk < 5632) { src = wv; dst = w16 + (2 << 20); off = (size_t)(blk - 5120) * 2048; }
  else                 { src = wo; dst = wo16;            off = (size_t)(blk - 5632) * 2048; }
  const float4* s4 = (const float4*)(src + off) + t * 2;
  const float4 a = s4[0], bq = s4[1];
  union { short8 v; unsigned short u[8]; } p;
  p.u[0] = f2b(a.x);  p.u[1] = f2b(a.y);  p.u[2] = f2b(a.z);  p.u[3] = f2b(a.w);
  p.u[4] = f2b(bq.x); p.u[5] = f2b(bq.y); p.u[6] = f2b(bq.z); p.u[7] = f2b(bq.w);
  *(short8*)(dst + off + (size_t)t * 8) = p.v;
}

// ---------------------------------------------------------------------------
// qkv_gemm v2 (round-9 structure): C[8192,3072] = x16@w16^T, bf16.  128x128
// tile, BK=64, XOR-swizzled LDS -> conflict-free ds_read_b128.  Epilogue:
// q,k RoPE-fused (float2 cos/sin table); v -> vt[B,H,DH,S].
// ---------------------------------------------------------------------------
__global__ __launch_bounds__(256) void qkv_gemm(
    const unsigned short* __restrict__ x16, const unsigned short* __restrict__ w16,
    const int* __restrict__ tpos, const float2* __restrict__ cstab,
    unsigned short* __restrict__ qb, unsigned short* __restrict__ kb,
    unsigned short* __restrict__ vt) {
  __shared__ __align__(16) unsigned short As[128 * 64];   // 16 KB
  __shared__ __align__(16) unsigned short Bs[128 * 64];   // 16 KB

  const int blk = blockIdx.x;           // 64 m-tiles (fast) x 24 n-tiles
  const int m0 = (blk & 63) * 128;
  const int nblk = blk >> 6;
  const int mat = nblk >> 3;
  const int c0 = (nblk & 7) * 128;

  const int tid = threadIdx.x;
  const int lane = tid & 63, wave = tid >> 6;
  const int wm = (wave >> 1) * 64, wn = (wave & 1) * 64;
  const int quad = lane >> 4, l15 = lane & 15;

  const int srw = lane >> 3;
  const int scw = ((lane & 7) ^ srw) * 8;
  const unsigned short* ag = x16 + (size_t)(m0 + wave * 32 + srw) * DD + scw;
  const unsigned short* bg = w16 + (size_t)(nblk * 128 + wave * 32 + srw) * DD + scw;
  unsigned short* al = &As[wave * 2048];
  unsigned short* bl = &Bs[wave * 2048];

  const int rx = l15 & 7;               // read-side XOR (row&7 == l15&7)

  floatx4 acc[4][4] = {};

  for (int k0 = 0; k0 < DD; k0 += 64) {
    ASYNC16(ag + k0,           al);
    ASYNC16(ag + 8 * DD + k0,  al + 512);
    ASYNC16(ag + 16 * DD + k0, al + 1024);
    ASYNC16(ag + 24 * DD + k0, al + 1536);
    ASYNC16(bg + k0,           bl);
    ASYNC16(bg + 8 * DD + k0,  bl + 512);
    ASYNC16(bg + 16 * DD + k0, bl + 1024);
    ASYNC16(bg + 24 * DD + k0, bl + 1536);
    __syncthreads();
#pragma unroll
    for (int ks = 0; ks < 2; ++ks) {
      short8 af[4], bf[4];
#pragma unroll
      for (int mt = 0; mt < 4; ++mt)
        af[mt] = *(const short8*)&As[(wm + mt * 16 + l15) * 64 +
                                     (((ks * 4 + quad) ^ rx) * 8)];
#pragma unroll
      for (int nt = 0; nt < 4; ++nt)
        bf[nt] = *(const short8*)&Bs[(wn + nt * 16 + l15) * 64 +
                                     (((ks * 4 + quad) ^ rx) * 8)];
#pragma unroll
      for (int mt = 0; mt < 4; ++mt)
#pragma unroll
        for (int nt = 0; nt < 4; ++nt)
          acc[mt][nt] = MFMA16(af[mt], bf[nt], acc[mt][nt]);
    }
    __syncthreads();
  }

  if (mat < 2) {
    // q/k epilogue with fused RoPE (float2 table: one 8B load per d-pair).
    unsigned short* dst = (mat == 0) ? qb : kb;
    const int odd = l15 & 1;
#pragma unroll
    for (int mt = 0; mt < 4; ++mt) {
#pragma unroll
      for (int r = 0; r < 4; ++r) {
        const int row = m0 + wm + mt * 16 + quad * 4 + r;
        const int pos = tpos[row];
        const float2* ct = cstab + (pos << 5);
        const int b = row >> 11, s = row & (SS - 1);
#pragma unroll
        for (int nt = 0; nt < 4; ++nt) {
          const int d = nt * 16 + l15;
          const float2 cs = ct[d >> 1];
          const float self = acc[mt][nt][r];
          const float partner = __shfl_xor(self, 1, 64);
          // even d: e*cos - o*sin ; odd d: e*sin + o*cos
          const float o = odd ? (partner * cs.y + self * cs.x)
                              : (self * cs.x - partner * cs.y);
          const int c = c0 + wn + d;
          const int h = c >> 6;
          dst[(((size_t)(b * HH + h)) * SS + s) * DH + d] = f2b(o);
        }
      }
    }
  } else {
#pragma unroll
    for (int mt = 0; mt < 4; ++mt) {
#pragma unroll
      for (int nt = 0; nt < 4; ++nt) {
        const int c = c0 + wn + nt * 16 + l15;
        const int h = c >> 6, d = c & 63;
        const int row0 = m0 + wm + mt * 16 + quad * 4;
        const int b = row0 >> 11, s0 = row0 & (SS - 1);
        union { unsigned short u[4]; uint2 v2; } pk;
#pragma unroll
        for (int r = 0; r < 4; ++r) pk.u[r] = f2b(acc[mt][nt][r]);
        *(uint2*)&vt[(((size_t)(b * HH + h)) * DH + d) * SS + s0] = pk.v2;
      }
    }
  }
}

// ---------------------------------------------------------------------------
// attn (round-11 bodies EXACTLY; the round-12 ls[4] accumulator split
// regressed attn_split 83->98 us -- reverted).  32x32x16 MFMA, 4 waves x 32
// q-rows, KVBLK=64, swapped QK^T, in-register softmax, permlane32_swap PV
// A-frags, XOR-swizzled K/V LDS via global_load_lds.
//   attn_flash - one block per q-tile (fallback when workspace is small)
//   attn_split - heavy q-tiles (qp>=8) split over 2 blocks along K; partials
//                bf16 pO + fp32 pL; merge adds in fp32.
// ---------------------------------------------------------------------------

// schedule table for attn_split: 24 entries, descending work.
// ORD[u] = qp*4 + mode, mode: 0 = split half 0, 1 = split half 1, 2 = light.
static __device__ const unsigned char ORD[24] = {
    60, 61, 30, 56, 57, 52, 53, 26, 48, 49, 44, 45,
    22, 40, 41, 36, 37, 18, 32, 33, 14, 10, 6, 2};

__global__ __launch_bounds__(256, 4) void attn_flash(
    const unsigned short* __restrict__ q, const unsigned short* __restrict__ k,
    const unsigned short* __restrict__ vt, unsigned short* __restrict__ ao) {
  const int blk = blockIdx.x;          // (15-qp)*64 + bh  (bh fastest)
  const int bh = blk & 63, qp = 15 - (blk >> 6);
  const int b = bh >> 4, h = bh & 15;
  const size_t kvbase = (size_t)bh * SS * DH;
  const size_t vtbase = (size_t)bh * DH * SS;

  const int tid = threadIdx.x;
  const int lane = tid & 63, wv = tid >> 6;
  const int l31 = lane & 31, hl = lane >> 5;

  __shared__ __align__(16) unsigned short Ks[2][64 * 64];
  __shared__ __align__(16) unsigned short Vs[2][64 * 64];

  int srowi[2], sgc[2];
#pragma unroll
  for (int c = 0; c < 2; ++c) {
    const int i16 = (wv * 2 + c) * 64 + lane;
    srowi[c] = i16 >> 3;
    sgc[c] = (i16 & 7) ^ (srowi[c] & 7);
  }

#define STAGE(bi, kt)                                                         \
  do {                                                                        \
    ASYNC16(k + kvbase + (size_t)((kt) * 64 + srowi[0]) * DH + sgc[0] * 8,    \
            &Ks[bi][(wv * 2 + 0) * 512]);                                     \
    ASYNC16(k + kvbase + (size_t)((kt) * 64 + srowi[1]) * DH + sgc[1] * 8,    \
            &Ks[bi][(wv * 2 + 1) * 512]);                                     \
    ASYNC16(vt + vtbase + (size_t)srowi[0] * SS + (kt) * 64 + sgc[0] * 8,     \
            &Vs[bi][(wv * 2 + 0) * 512]);                                     \
    ASYNC16(vt + vtbase + (size_t)srowi[1] * SS + (kt) * 64 + sgc[1] * 8,     \
            &Vs[bi][(wv * 2 + 1) * 512]);                                     \
  } while (0)

  const int Q0 = qp * 128;
  const int nt = 2 * qp + 2;
  const int ew = 2 * qp + (wv >> 1);
  const int qa = Q0 + wv * 32 + l31;

  short8 qf[4];
#pragma unroll
  for (int ks = 0; ks < 4; ++ks)
    qf[ks] = *(const short8*)(q + kvbase + (size_t)qa * DH + ks * 16 + hl * 8);

  floatx16 oacc[2] = {};
  float lsum = 0.f;

  STAGE(0, 0);
  __syncthreads();

  for (int kt = 0; kt < nt; ++kt) {
    const int cur = kt & 1;
    if (kt + 1 < nt) STAGE((kt + 1) & 1, kt + 1);

    if (kt <= ew) {
      floatx16 st[2] = {};
      __builtin_amdgcn_s_setprio(1);
#pragma unroll
      for (int g = 0; g < 2; ++g) {
        const int row = g * 32 + l31;
        const int rx = row & 7;
#pragma unroll
        for (int ks = 0; ks < 4; ++ks) {
          const int u = row * 8 + ((ks * 2 + hl) ^ rx);
          short8 kf = *(const short8*)&Ks[cur][u * 8];
          st[g] = MFMA32(kf, qf[ks], st[g]);
        }
      }
      __builtin_amdgcn_s_setprio(0);

      float pv[2][16];
      if (kt == ew) {
#pragma unroll
        for (int g = 0; g < 2; ++g)
#pragma unroll
          for (int r = 0; r < 16; ++r) {
            const int key = kt * 64 + g * 32 + (r & 3) + 8 * (r >> 2) + 4 * hl;
            const float e = (key > qa)
                ? 0.f
                : exp2f(st[g][r] * 0.18033688011112042f - 11.541560327111707f);
            pv[g][r] = e;
            lsum += e;
          }
      } else {
#pragma unroll
        for (int g = 0; g < 2; ++g)
#pragma unroll
          for (int r = 0; r < 16; ++r) {
            const float e =
                exp2f(st[g][r] * 0.18033688011112042f - 11.541560327111707f);
            pv[g][r] = e;
            lsum += e;
          }
      }

      unsigned int W[2][4][2];
#pragma unroll
      for (int g = 0; g < 2; ++g)
#pragma unroll
        for (int bb = 0; bb < 4; ++bb)
#pragma unroll
          for (int w = 0; w < 2; ++w)
            asm("v_cvt_pk_bf16_f32 %0, %1, %2"
                : "=v"(W[g][bb][w])
                : "v"(pv[g][4 * bb + 2 * w]), "v"(pv[g][4 * bb + 2 * w + 1]));

#pragma unroll
      for (int ks = 0; ks < 4; ++ks) {
        const int g = ks >> 1, c2 = (ks & 1) * 2;
        const uint2v w0 = __builtin_amdgcn_permlane32_swap(
            W[g][c2][0], W[g][c2 + 1][0], false, false);
        const uint2v w1 = __builtin_amdgcn_permlane32_swap(
            W[g][c2][1], W[g][c2 + 1][1], false, false);
        union { unsigned int u[4]; short8 s; } pa;
        pa.u[0] = w0.x;
        pa.u[1] = w1.x;
        pa.u[2] = w0.y;
        pa.u[3] = w1.y;
        __builtin_amdgcn_s_setprio(1);
#pragma unroll
        for (int dg = 0; dg < 2; ++dg) {
          const int row = dg * 32 + l31;
          const int u = row * 8 + ((ks * 2 + hl) ^ (row & 7));
          short8 vf = *(const short8*)&Vs[cur][u * 8];
          oacc[dg] = MFMA32(pa.s, vf, oacc[dg]);
        }
        __builtin_amdgcn_s_setprio(0);
      }
    }
    __syncthreads();
  }

  const float rs = lsum + __shfl_xor(lsum, 32, 64);
  const float linv = 1.0f / rs;
#pragma unroll
  for (int r = 0; r < 16; ++r) {
    const int ql = (r & 3) + 8 * (r >> 2) + 4 * hl;
    const float li = __shfl(linv, ql, 64);
    const int qabs = Q0 + wv * 32 + ql;
#pragma unroll
    for (int dg = 0; dg < 2; ++dg) {
      const int d = dg * 32 + l31;
      ao[((size_t)(b * SS + qabs)) * DD + h * DH + d] = f2b(oacc[dg][r] * li);
    }
  }
#undef STAGE
}

__global__ __launch_bounds__(256, 4) void attn_split(
    const unsigned short* __restrict__ q, const unsigned short* __restrict__ k,
    const unsigned short* __restrict__ vt, unsigned short* __restrict__ ao,
    unsigned short* __restrict__ pO, float* __restrict__ pL) {
  const int blk = blockIdx.x;              // u*64 + bh (bh fastest)
  const int bh = blk & 63, u = blk >> 6;
  const int ent = ORD[u];
  const int qp = ent >> 2, mode = ent & 3;
  const int b = bh >> 4, h = bh & 15;
  const size_t kvbase = (size_t)bh * SS * DH;
  const size_t vtbase = (size_t)bh * DH * SS;

  const int kb = (mode == 1) ? (qp + 1) : 0;
  const int ke = (mode == 0) ? (qp + 1) : (2 * qp + 2);

  const int tid = threadIdx.x;
  const int lane = tid & 63, wv = tid >> 6;
  const int l31 = lane & 31, hl = lane >> 5;

  __shared__ __align__(16) unsigned short Ks[2][64 * 64];
  __shared__ __align__(16) unsigned short Vs[2][64 * 64];

  int srowi[2], sgc[2];
#pragma unroll
  for (int c = 0; c < 2; ++c) {
    const int i16 = (wv * 2 + c) * 64 + lane;
    srowi[c] = i16 >> 3;
    sgc[c] = (i16 & 7) ^ (srowi[c] & 7);
  }

#define STAGE(bi, kt)                                                         \
  do {                                                                        \
    ASYNC16(k + kvbase + (size_t)((kt) * 64 + srowi[0]) * DH + sgc[0] * 8,    \
            &Ks[bi][(wv * 2 + 0) * 512]);                                     \
    ASYNC16(k + kvbase + (size_t)((kt) * 64 + srowi[1]) * DH + sgc[1] * 8,    \
            &Ks[bi][(wv * 2 + 1) * 512]);                                     \
    ASYNC16(vt + vtbase + (size_t)srowi[0] * SS + (kt) * 64 + sgc[0] * 8,     \
            &Vs[bi][(wv * 2 + 0) * 512]);                                     \
    ASYNC16(vt + vtbase + (size_t)srowi[1] * SS + (kt) * 64 + sgc[1] * 8,     \
            &Vs[bi][(wv * 2 + 1) * 512]);                                     \
  } while (0)

  const int Q0 = qp * 128;
  const int ew = 2 * qp + (wv >> 1);       // wave's edge tile (global index)
  const int qa = Q0 + wv * 32 + l31;

  short8 qf[4];
#pragma unroll
  for (int ks = 0; ks < 4; ++ks)
    qf[ks] = *(const short8*)(q + kvbase + (size_t)qa * DH + ks * 16 + hl * 8);

  floatx16 oacc[2] = {};
  float lsum = 0.f;

  STAGE(0, kb);
  __syncthreads();

  for (int g0 = kb; g0 < ke; ++g0) {
    const int cur = (g0 - kb) & 1;
    if (g0 + 1 < ke) STAGE((g0 - kb + 1) & 1, g0 + 1);

    if (g0 <= ew) {
      floatx16 st[2] = {};
      __builtin_amdgcn_s_setprio(1);
#pragma unroll
      for (int g = 0; g < 2; ++g) {
        const int row = g * 32 + l31;
        const int rx = row & 7;
#pragma unroll
        for (int ks = 0; ks < 4; ++ks) {
          const int uu = row * 8 + ((ks * 2 + hl) ^ rx);
          short8 kf = *(const short8*)&Ks[cur][uu * 8];
          st[g] = MFMA32(kf, qf[ks], st[g]);
        }
      }
      __builtin_amdgcn_s_setprio(0);

      float pv[2][16];
      if (g0 == ew) {
#pragma unroll
        for (int g = 0; g < 2; ++g)
#pragma unroll
          for (int r = 0; r < 16; ++r) {
            const int key = g0 * 64 + g * 32 + (r & 3) + 8 * (r >> 2) + 4 * hl;
            const float e = (key > qa)
                ? 0.f
                : exp2f(st[g][r] * 0.18033688011112042f - 11.541560327111707f);
            pv[g][r] = e;
            lsum += e;
          }
      } else {
#pragma unroll
        for (int g = 0; g < 2; ++g)
#pragma unroll
          for (int r = 0; r < 16; ++r) {
            const float e =
                exp2f(st[g][r] * 0.18033688011112042f - 11.541560327111707f);
            pv[g][r] = e;
            lsum += e;
          }
      }

      unsigned int W[2][4][2];
#pragma unroll
      for (int g = 0; g < 2; ++g)
#pragma unroll
        for (int bb = 0; bb < 4; ++bb)
#pragma unroll
          for (int w = 0; w < 2; ++w)
            asm("v_cvt_pk_bf16_f32 %0, %1, %2"
                : "=v"(W[g][bb][w])
                : "v"(pv[g][4 * bb + 2 * w]), "v"(pv[g][4 * bb + 2 * w + 1]));

#pragma unroll
      for (int ks = 0; ks < 4; ++ks) {
        const int g = ks >> 1, c2 = (ks & 1) * 2;
        const uint2v w0 = __builtin_amdgcn_permlane32_swap(
            W[g][c2][0], W[g][c2 + 1][0], false, false);
        const uint2v w1 = __builtin_amdgcn_permlane32_swap(
            W[g][c2][1], W[g][c2 + 1][1], false, false);
        union { unsigned int uu[4]; short8 s; } pa;
        pa.uu[0] = w0.x;
        pa.uu[1] = w1.x;
        pa.uu[2] = w0.y;
        pa.uu[3] = w1.y;
        __builtin_amdgcn_s_setprio(1);
#pragma unroll
        for (int dg = 0; dg < 2; ++dg) {
          const int row = dg * 32 + l31;
          const int uu = row * 8 + ((ks * 2 + hl) ^ (row & 7));
          short8 vf = *(const short8*)&Vs[cur][uu * 8];
          oacc[dg] = MFMA32(pa.s, vf, oacc[dg]);
        }
        __builtin_amdgcn_s_setprio(0);
      }
    }
    __syncthreads();
  }

  if (mode == 2) {
    const float rs = lsum + __shfl_xor(lsum, 32, 64);
    const float linv = 1.0f / rs;
#pragma unroll
    for (int r = 0; r < 16; ++r) {
      const int ql = (r & 3) + 8 * (r >> 2) + 4 * hl;
      const float li = __shfl(linv, ql, 64);
      const int qabs = Q0 + wv * 32 + ql;
#pragma unroll
      for (int dg = 0; dg < 2; ++dg) {
        const int d = dg * 32 + l31;
        ao[((size_t)(b * SS + qabs)) * DD + h * DH + d] = f2b(oacc[dg][r] * li);
      }
    }
  } else {
    // partial store: bf16 unnormalized pV sums + fp32 row-sum
    const int slab = ((qp - 8) * 2 + mode) * 64 + bh;
    const float rs = lsum + __shfl_xor(lsum, 32, 64);
    if (hl == 0) pL[slab * 128 + wv * 32 + l31] = rs;
#pragma unroll
    for (int r = 0; r < 16; ++r) {
      const int ql = (r & 3) + 8 * (r >> 2) + 4 * hl;
      const int row = wv * 32 + ql;
#pragma unroll
      for (int dg = 0; dg < 2; ++dg) {
        const int d = dg * 32 + l31;
        pO[((size_t)slab * 128 + row) * 64 + d] = f2b(oacc[dg][r]);
      }
    }
  }
#undef STAGE
}

// merge the two K-halves of each heavy q-tile: ao = (O0+O1)/(l0+l1)
__global__ __launch_bounds__(256) void attn_merge(
    const unsigned short* __restrict__ pO, const float* __restrict__ pL,
    unsigned short* __restrict__ ao) {
  const int flat = blockIdx.x * 256 + threadIdx.x;   // 0..131071
  const int row = flat >> 1, dh = (flat & 1) * 32;   // 65536 rows x 2 halves
  const int bh = row >> 10, p = (row >> 7) & 7, rl = row & 127;
  const int b = bh >> 4, h = bh & 15;
  const int qabs = 1024 + p * 128 + rl;              // qp = 8+p
  const int slab0 = (p * 2 + 0) * 64 + bh;
  const int slab1 = slab0 + 64;
  const float l = pL[slab0 * 128 + rl] + pL[slab1 * 128 + rl];
  const float inv = 1.0f / l;
  const unsigned short* o0 = &pO[((size_t)slab0 * 128 + rl) * 64 + dh];
  const unsigned short* o1 = &pO[((size_t)slab1 * 128 + rl) * 64 + dh];
  unsigned short* dst = &ao[((size_t)(b * SS + qabs)) * DD + h * DH + dh];
#pragma unroll
  for (int j = 0; j < 4; ++j) {
    union { short8 v; unsigned short u[8]; } a8, c8, pk;
    a8.v = *(const short8*)(o0 + 8 * j);
    c8.v = *(const short8*)(o1 + 8 * j);
#pragma unroll
    for (int e = 0; e < 8; ++e)
      pk.u[e] = f2b((b2f(a8.u[e]) + b2f(c8.u[e])) * inv);
    *(short8*)(dst + 8 * j) = pk.v;
  }
}

// ---------------------------------------------------------------------------
// o_gemm v2 (unchanged from round 9): out[8192,1024](fp32) = ab @ wo16^T
// (bf16).  BK=64 + XOR-swizzled LDS.
// ---------------------------------------------------------------------------
__global__ __launch_bounds__(256) void o_gemm(
    const unsigned short* __restrict__ a, const unsigned short* __restrict__ w16,
    float* __restrict__ out) {
  __shared__ __align__(16) unsigned short As[128 * 64];
  __shared__ __align__(16) unsigned short Bs[128 * 64];

  const int blk = blockIdx.x;          // 64 m x 8 n
  const int m0 = (blk >> 3) * 128;
  const int n0 = (blk & 7) * 128;

  const int tid = threadIdx.x;
  const int lane = tid & 63, wave = tid >> 6;
  const int wm = (wave >> 1) * 64, wn = (wave & 1) * 64;
  const int quad = lane >> 4, l15 = lane & 15;

  const int srw = lane >> 3;
  const int scw = ((lane & 7) ^ srw) * 8;
  const unsigned short* ag = a + (size_t)(m0 + wave * 32 + srw) * DD + scw;
  const unsigned short* bg = w16 + (size_t)(n0 + wave * 32 + srw) * DD + scw;
  unsigned short* al = &As[wave * 2048];
  unsigned short* bl = &Bs[wave * 2048];

  const int rx = l15 & 7;

  floatx4 acc[4][4] = {};

  for (int k0 = 0; k0 < DD; k0 += 64) {
    ASYNC16(ag + k0,           al);
    ASYNC16(ag + 8 * DD + k0,  al + 512);
    ASYNC16(ag + 16 * DD + k0, al + 1024);
    ASYNC16(ag + 24 * DD + k0, al + 1536);
    ASYNC16(bg + k0,           bl);
    ASYNC16(bg + 8 * DD + k0,  bl + 512);
    ASYNC16(bg + 16 * DD + k0, bl + 1024);
    ASYNC16(bg + 24 * DD + k0, bl + 1536);
    __syncthreads();
#pragma unroll
    for (int ks = 0; ks < 2; ++ks) {
      short8 af[4], bf[4];
#pragma unroll
      for (int mt = 0; mt < 4; ++mt)
        af[mt] = *(const short8*)&As[(wm + mt * 16 + l15) * 64 +
                                     (((ks * 4 + quad) ^ rx) * 8)];
#pragma unroll
      for (int nt = 0; nt < 4; ++nt)
        bf[nt] = *(const short8*)&Bs[(wn + nt * 16 + l15) * 64 +
                                     (((ks * 4 + quad) ^ rx) * 8)];
#pragma unroll
      for (int mt = 0; mt < 4; ++mt)
#pragma unroll
        for (int nt = 0; nt < 4; ++nt)
          acc[mt][nt] = MFMA16(af[mt], bf[nt], acc[mt][nt]);
    }
    __syncthreads();
  }

#pragma unroll
  for (int mt = 0; mt < 4; ++mt) {
#pragma unroll
    for (int nt = 0; nt < 4; ++nt) {
#pragma unroll
      for (int r = 0; r < 4; ++r) {
        const int row = m0 + wm + mt * 16 + quad * 4 + r;
        const int col = n0 + wn + nt * 16 + l15;
        out[(size_t)row * DD + col] = acc[mt][nt][r];
      }
    }
  }
}

extern "C" void kernel_launch(void* const* d_in, const int* in_sizes, int n_in,
                              void* d_out, int out_size, void* d_ws, size_t ws_size,
                              hipStream_t stream) {
  const float* x  = (const float*)d_in[0];
  const int* tpos = (const int*)d_in[1];
  const float* wq = (const float*)d_in[2];
  const float* wk = (const float*)d_in[3];
  const float* wv = (const float*)d_in[4];
  const float* wo = (const float*)d_in[5];

  const size_t N = (size_t)BB * SS * DD;           // 8,388,608
  unsigned short* qb  = (unsigned short*)d_out;    // bf16 q [B,H,S,DH]   (16.8 MB)
  unsigned short* w16 = qb + N;                    // bf16 q|k|v weights  (6.3 MB)
  float2* cstab = (float2*)(w16 + (3u << 20));     // 2048x32 {cos,sin}   (512 KB)
  unsigned short* kb   = (unsigned short*)d_ws;    // bf16 k [B,H,S,DH]
  unsigned short* vb   = kb + N;                   // bf16 v^T [B,H,DH,S]
  unsigned short* ab   = vb + N;                   // bf16 attn [B,S,D]
  unsigned short* wo16 = ab + N;                   // bf16 wo
  unsigned short* x16  = ab;                       // alias: dead before attn writes ab
  float* out = (float*)d_out;

  // split-K attention partials (bf16 pO + fp32 pL), after wo16.
  const size_t base = (3 * N + (1u << 20)) * sizeof(unsigned short); // 52.43 MB
  const size_t WS_NEED = base + 8388608ull * sizeof(unsigned short)
                              + 131072ull * sizeof(float);

  cvt_all<<<6400, 256, 0, stream>>>(x, wq, wk, wv, wo, x16, w16, wo16, cstab);
  qkv_gemm<<<64 * 24, 256, 0, stream>>>(x16, w16, tpos, cstab, qb, kb, vb);
  if (ws_size >= WS_NEED) {
    unsigned short* pO = (unsigned short*)((char*)d_ws + base);
    float* pL = (float*)(pO + 8388608);
    attn_split<<<24 * 64, 256, 0, stream>>>(qb, kb, vb, ab, pO, pL);
    attn_merge<<<512, 256, 0, stream>>>(pO, pL, ab);
  } else {
    attn_flash<<<16 * 64, 256, 0, stream>>>(qb, kb, vb, ab);
  }
  o_gemm<<<64 * 8, 256, 0, stream>>>(ab, wo16, out);
}

// Round 14
// 265.023 us; speedup vs baseline: 1.0720x; 1.0073x over previous
//
#include <hip/hip_runtime.h>

#define BB 4
#define SS 2048
#define DD 1024
#define HH 16
#define DH 64

typedef __attribute__((ext_vector_type(8))) short short8;
typedef __attribute__((ext_vector_type(4))) float floatx4;
typedef __attribute__((ext_vector_type(16))) float floatx16;
typedef __attribute__((ext_vector_type(2))) unsigned int uint2v;

static __device__ __forceinline__ float b2f(unsigned short u) {
  union { unsigned int i; float f; } c; c.i = ((unsigned int)u) << 16; return c.f;
}
static __device__ __forceinline__ unsigned short f2b(float f) {
  union { float ff; unsigned int i; } c; c.ff = f;
  unsigned int x = c.i;
  return (unsigned short)((x + 0x7fffu + ((x >> 16) & 1u)) >> 16);
}

#define MFMA16(a, b, c) __builtin_amdgcn_mfma_f32_16x16x32_bf16((a), (b), (c), 0, 0, 0)
#define MFMA32(a, b, c) __builtin_amdgcn_mfma_f32_32x32x16_bf16((a), (b), (c), 0, 0, 0)

// async global->LDS, 16 B per lane; LDS dest = wave-uniform base + lane*16
#define ASYNC16(g, l)                                                        \
  __builtin_amdgcn_global_load_lds(                                          \
      (const __attribute__((address_space(1))) unsigned int*)(g),            \
      (__attribute__((address_space(3))) unsigned int*)(l), 16, 0, 0)

// ---------------------------------------------------------------------------
// cvt_all: one-shot fp32 -> bf16 for x and the 4 weight matrices, PLUS
// cos/sin RoPE tables (2048 pos x 32 j) in fp32 for the fused qkv epilogue.
// ---------------------------------------------------------------------------
__global__ __launch_bounds__(256) void cvt_all(
    const float* __restrict__ x, const float* __restrict__ wq,
    const float* __restrict__ wk, const float* __restrict__ wv,
    const float* __restrict__ wo,
    unsigned short* __restrict__ x16, unsigned short* __restrict__ w16,
    unsigned short* __restrict__ wo16,
    float* __restrict__ costab, float* __restrict__ sintab) {
  const int blk = blockIdx.x;
  const int t = threadIdx.x;

  if (blk >= 6144) {                     // RoPE table gen: 256 blocks
    const int idx = ((blk - 6144) << 8) + t;        // 0..65535 = pos*32 + j
    const int j = idx & 31;
    const float pf = (float)(idx >> 5);
    const float ang = pf * exp2f(-0.41524101186091903f * (float)j);
    float sv, cv;
    sincosf(ang, &sv, &cv);
    costab[idx] = cv;
    sintab[idx] = sv;
    return;
  }

  const float* src;
  unsigned short* dst;
  size_t off;
  if (blk < 4096)      { src = x;  dst = x16;             off = (size_t)blk * 2048; }
  else if (blk < 4608) { src = wq; dst = w16;             off = (size_t)(blk - 4096) * 2048; }
  else if (blk < 5120) { src = wk; dst = w16 + (1 << 20); off = (size_t)(blk - 4608) * 2048; }
  else if (blk < 5632) { src = wv; dst = w16 + (2 << 20); off = (size_t)(blk - 5120) * 2048; }
  else                 { src = wo; dst = wo16;            off = (size_t)(blk - 5632) * 2048; }
  const float4* s4 = (const float4*)(src + off) + t * 2;
  const float4 a = s4[0], bq = s4[1];
  union { short8 v; unsigned short u[8]; } p;
  p.u[0] = f2b(a.x);  p.u[1] = f2b(a.y);  p.u[2] = f2b(a.z);  p.u[3] = f2b(a.w);
  p.u[4] = f2b(bq.x); p.u[5] = f2b(bq.y); p.u[6] = f2b(bq.z); p.u[7] = f2b(bq.w);
  *(short8*)(dst + off + (size_t)t * 8) = p.v;
}

// ---------------------------------------------------------------------------
// qkv_gemm v2: C[8192,3072] = x16@w16^T, bf16.  128x128 tile, BK=64,
// XOR-swizzled LDS -> conflict-free ds_read_b128.  Epilogue: q,k RoPE-fused;
// v -> vt[B,H,DH,S].
// ---------------------------------------------------------------------------
__global__ __launch_bounds__(256) void qkv_gemm(
    const unsigned short* __restrict__ x16, const unsigned short* __restrict__ w16,
    const int* __restrict__ tpos,
    const float* __restrict__ costab, const float* __restrict__ sintab,
    unsigned short* __restrict__ qb, unsigned short* __restrict__ kb,
    unsigned short* __restrict__ vt) {
  __shared__ __align__(16) unsigned short As[128 * 64];   // 16 KB
  __shared__ __align__(16) unsigned short Bs[128 * 64];   // 16 KB

  const int blk = blockIdx.x;           // 64 m-tiles (fast) x 24 n-tiles
  const int m0 = (blk & 63) * 128;
  const int nblk = blk >> 6;
  const int mat = nblk >> 3;
  const int c0 = (nblk & 7) * 128;

  const int tid = threadIdx.x;
  const int lane = tid & 63, wave = tid >> 6;
  const int wm = (wave >> 1) * 64, wn = (wave & 1) * 64;
  const int quad = lane >> 4, l15 = lane & 15;

  const int srw = lane >> 3;
  const int scw = ((lane & 7) ^ srw) * 8;
  const unsigned short* ag = x16 + (size_t)(m0 + wave * 32 + srw) * DD + scw;
  const unsigned short* bg = w16 + (size_t)(nblk * 128 + wave * 32 + srw) * DD + scw;
  unsigned short* al = &As[wave * 2048];
  unsigned short* bl = &Bs[wave * 2048];

  const int rx = l15 & 7;               // read-side XOR (row&7 == l15&7)

  floatx4 acc[4][4] = {};

  for (int k0 = 0; k0 < DD; k0 += 64) {
    ASYNC16(ag + k0,           al);
    ASYNC16(ag + 8 * DD + k0,  al + 512);
    ASYNC16(ag + 16 * DD + k0, al + 1024);
    ASYNC16(ag + 24 * DD + k0, al + 1536);
    ASYNC16(bg + k0,           bl);
    ASYNC16(bg + 8 * DD + k0,  bl + 512);
    ASYNC16(bg + 16 * DD + k0, bl + 1024);
    ASYNC16(bg + 24 * DD + k0, bl + 1536);
    __syncthreads();
#pragma unroll
    for (int ks = 0; ks < 2; ++ks) {
      short8 af[4], bf[4];
#pragma unroll
      for (int mt = 0; mt < 4; ++mt)
        af[mt] = *(const short8*)&As[(wm + mt * 16 + l15) * 64 +
                                     (((ks * 4 + quad) ^ rx) * 8)];
#pragma unroll
      for (int nt = 0; nt < 4; ++nt)
        bf[nt] = *(const short8*)&Bs[(wn + nt * 16 + l15) * 64 +
                                     (((ks * 4 + quad) ^ rx) * 8)];
#pragma unroll
      for (int mt = 0; mt < 4; ++mt)
#pragma unroll
        for (int nt = 0; nt < 4; ++nt)
          acc[mt][nt] = MFMA16(af[mt], bf[nt], acc[mt][nt]);
    }
    __syncthreads();
  }

  if (mat < 2) {
    // q/k epilogue with fused RoPE.
    unsigned short* dst = (mat == 0) ? qb : kb;
    const int odd = l15 & 1;
#pragma unroll
    for (int mt = 0; mt < 4; ++mt) {
#pragma unroll
      for (int r = 0; r < 4; ++r) {
        const int row = m0 + wm + mt * 16 + quad * 4 + r;
        const int pos = tpos[row];
        const float* ct = costab + (pos << 5);
        const float* st = sintab + (pos << 5);
        const int b = row >> 11, s = row & (SS - 1);
#pragma unroll
        for (int nt = 0; nt < 4; ++nt) {
          const int d = nt * 16 + l15;
          const int j = d >> 1;
          const float cv = ct[j], sv = st[j];
          const float self = acc[mt][nt][r];
          const float partner = __shfl_xor(self, 1, 64);
          const float o = odd ? (partner * sv + self * cv)
                              : (self * cv - partner * sv);
          const int c = c0 + wn + d;
          const int h = c >> 6;
          dst[(((size_t)(b * HH + h)) * SS + s) * DH + d] = f2b(o);
        }
      }
    }
  } else {
#pragma unroll
    for (int mt = 0; mt < 4; ++mt) {
#pragma unroll
      for (int nt = 0; nt < 4; ++nt) {
        const int c = c0 + wn + nt * 16 + l15;
        const int h = c >> 6, d = c & 63;
        const int row0 = m0 + wm + mt * 16 + quad * 4;
        const int b = row0 >> 11, s0 = row0 & (SS - 1);
        union { unsigned short u[4]; uint2 v2; } pk;
#pragma unroll
        for (int r = 0; r < 4; ++r) pk.u[r] = f2b(acc[mt][nt][r]);
        *(uint2*)&vt[(((size_t)(b * HH + h)) * DH + d) * SS + s0] = pk.v2;
      }
    }
  }
}

// ---------------------------------------------------------------------------
// attn (round-11 bodies EXACTLY -- session-best 265.6 us config).
// 32x32x16 MFMA, 4 waves x 32 q-rows, KVBLK=64, swapped QK^T, in-register
// softmax, permlane32_swap PV A-frags, XOR-swizzled K/V LDS via
// global_load_lds.
//   attn_flash - one block per q-tile (fallback when workspace is small)
//   attn_split - heavy q-tiles (qp>=8) split over 2 blocks along K; partials
//                bf16 pO + fp32 pL; merge adds in fp32.
// ---------------------------------------------------------------------------

// schedule table for attn_split: 24 entries, descending work.
// ORD[u] = qp*4 + mode, mode: 0 = split half 0, 1 = split half 1, 2 = light.
static __device__ const unsigned char ORD[24] = {
    60, 61, 30, 56, 57, 52, 53, 26, 48, 49, 44, 45,
    22, 40, 41, 36, 37, 18, 32, 33, 14, 10, 6, 2};

__global__ __launch_bounds__(256, 4) void attn_flash(
    const unsigned short* __restrict__ q, const unsigned short* __restrict__ k,
    const unsigned short* __restrict__ vt, unsigned short* __restrict__ ao) {
  const int blk = blockIdx.x;          // (15-qp)*64 + bh  (bh fastest)
  const int bh = blk & 63, qp = 15 - (blk >> 6);
  const int b = bh >> 4, h = bh & 15;
  const size_t kvbase = (size_t)bh * SS * DH;
  const size_t vtbase = (size_t)bh * DH * SS;

  const int tid = threadIdx.x;
  const int lane = tid & 63, wv = tid >> 6;
  const int l31 = lane & 31, hl = lane >> 5;

  __shared__ __align__(16) unsigned short Ks[2][64 * 64];
  __shared__ __align__(16) unsigned short Vs[2][64 * 64];

  int srowi[2], sgc[2];
#pragma unroll
  for (int c = 0; c < 2; ++c) {
    const int i16 = (wv * 2 + c) * 64 + lane;
    srowi[c] = i16 >> 3;
    sgc[c] = (i16 & 7) ^ (srowi[c] & 7);
  }

#define STAGE(bi, kt)                                                         \
  do {                                                                        \
    ASYNC16(k + kvbase + (size_t)((kt) * 64 + srowi[0]) * DH + sgc[0] * 8,    \
            &Ks[bi][(wv * 2 + 0) * 512]);                                     \
    ASYNC16(k + kvbase + (size_t)((kt) * 64 + srowi[1]) * DH + sgc[1] * 8,    \
            &Ks[bi][(wv * 2 + 1) * 512]);                                     \
    ASYNC16(vt + vtbase + (size_t)srowi[0] * SS + (kt) * 64 + sgc[0] * 8,     \
            &Vs[bi][(wv * 2 + 0) * 512]);                                     \
    ASYNC16(vt + vtbase + (size_t)srowi[1] * SS + (kt) * 64 + sgc[1] * 8,     \
            &Vs[bi][(wv * 2 + 1) * 512]);                                     \
  } while (0)

  const int Q0 = qp * 128;
  const int nt = 2 * qp + 2;
  const int ew = 2 * qp + (wv >> 1);
  const int qa = Q0 + wv * 32 + l31;

  short8 qf[4];
#pragma unroll
  for (int ks = 0; ks < 4; ++ks)
    qf[ks] = *(const short8*)(q + kvbase + (size_t)qa * DH + ks * 16 + hl * 8);

  floatx16 oacc[2] = {};
  float lsum = 0.f;

  STAGE(0, 0);
  __syncthreads();

  for (int kt = 0; kt < nt; ++kt) {
    const int cur = kt & 1;
    if (kt + 1 < nt) STAGE((kt + 1) & 1, kt + 1);

    if (kt <= ew) {
      floatx16 st[2] = {};
      __builtin_amdgcn_s_setprio(1);
#pragma unroll
      for (int g = 0; g < 2; ++g) {
        const int row = g * 32 + l31;
        const int rx = row & 7;
#pragma unroll
        for (int ks = 0; ks < 4; ++ks) {
          const int u = row * 8 + ((ks * 2 + hl) ^ rx);
          short8 kf = *(const short8*)&Ks[cur][u * 8];
          st[g] = MFMA32(kf, qf[ks], st[g]);
        }
      }
      __builtin_amdgcn_s_setprio(0);

      float pv[2][16];
      if (kt == ew) {
#pragma unroll
        for (int g = 0; g < 2; ++g)
#pragma unroll
          for (int r = 0; r < 16; ++r) {
            const int key = kt * 64 + g * 32 + (r & 3) + 8 * (r >> 2) + 4 * hl;
            const float e = (key > qa)
                ? 0.f
                : exp2f(st[g][r] * 0.18033688011112042f - 11.541560327111707f);
            pv[g][r] = e;
            lsum += e;
          }
      } else {
#pragma unroll
        for (int g = 0; g < 2; ++g)
#pragma unroll
          for (int r = 0; r < 16; ++r) {
            const float e =
                exp2f(st[g][r] * 0.18033688011112042f - 11.541560327111707f);
            pv[g][r] = e;
            lsum += e;
          }
      }

      unsigned int W[2][4][2];
#pragma unroll
      for (int g = 0; g < 2; ++g)
#pragma unroll
        for (int bb = 0; bb < 4; ++bb)
#pragma unroll
          for (int w = 0; w < 2; ++w)
            asm("v_cvt_pk_bf16_f32 %0, %1, %2"
                : "=v"(W[g][bb][w])
                : "v"(pv[g][4 * bb + 2 * w]), "v"(pv[g][4 * bb + 2 * w + 1]));

#pragma unroll
      for (int ks = 0; ks < 4; ++ks) {
        const int g = ks >> 1, c2 = (ks & 1) * 2;
        const uint2v w0 = __builtin_amdgcn_permlane32_swap(
            W[g][c2][0], W[g][c2 + 1][0], false, false);
        const uint2v w1 = __builtin_amdgcn_permlane32_swap(
            W[g][c2][1], W[g][c2 + 1][1], false, false);
        union { unsigned int u[4]; short8 s; } pa;
        pa.u[0] = w0.x;
        pa.u[1] = w1.x;
        pa.u[2] = w0.y;
        pa.u[3] = w1.y;
        __builtin_amdgcn_s_setprio(1);
#pragma unroll
        for (int dg = 0; dg < 2; ++dg) {
          const int row = dg * 32 + l31;
          const int u = row * 8 + ((ks * 2 + hl) ^ (row & 7));
          short8 vf = *(const short8*)&Vs[cur][u * 8];
          oacc[dg] = MFMA32(pa.s, vf, oacc[dg]);
        }
        __builtin_amdgcn_s_setprio(0);
      }
    }
    __syncthreads();
  }

  const float rs = lsum + __shfl_xor(lsum, 32, 64);
  const float linv = 1.0f / rs;
#pragma unroll
  for (int r = 0; r < 16; ++r) {
    const int ql = (r & 3) + 8 * (r >> 2) + 4 * hl;
    const float li = __shfl(linv, ql, 64);
    const int qabs = Q0 + wv * 32 + ql;
#pragma unroll
    for (int dg = 0; dg < 2; ++dg) {
      const int d = dg * 32 + l31;
      ao[((size_t)(b * SS + qabs)) * DD + h * DH + d] = f2b(oacc[dg][r] * li);
    }
  }
#undef STAGE
}

__global__ __launch_bounds__(256, 4) void attn_split(
    const unsigned short* __restrict__ q, const unsigned short* __restrict__ k,
    const unsigned short* __restrict__ vt, unsigned short* __restrict__ ao,
    unsigned short* __restrict__ pO, float* __restrict__ pL) {
  const int blk = blockIdx.x;              // u*64 + bh (bh fastest)
  const int bh = blk & 63, u = blk >> 6;
  const int ent = ORD[u];
  const int qp = ent >> 2, mode = ent & 3;
  const int b = bh >> 4, h = bh & 15;
  const size_t kvbase = (size_t)bh * SS * DH;
  const size_t vtbase = (size_t)bh * DH * SS;

  const int kb = (mode == 1) ? (qp + 1) : 0;
  const int ke = (mode == 0) ? (qp + 1) : (2 * qp + 2);

  const int tid = threadIdx.x;
  const int lane = tid & 63, wv = tid >> 6;
  const int l31 = lane & 31, hl = lane >> 5;

  __shared__ __align__(16) unsigned short Ks[2][64 * 64];
  __shared__ __align__(16) unsigned short Vs[2][64 * 64];

  int srowi[2], sgc[2];
#pragma unroll
  for (int c = 0; c < 2; ++c) {
    const int i16 = (wv * 2 + c) * 64 + lane;
    srowi[c] = i16 >> 3;
    sgc[c] = (i16 & 7) ^ (srowi[c] & 7);
  }

#define STAGE(bi, kt)                                                         \
  do {                                                                        \
    ASYNC16(k + kvbase + (size_t)((kt) * 64 + srowi[0]) * DH + sgc[0] * 8,    \
            &Ks[bi][(wv * 2 + 0) * 512]);                                     \
    ASYNC16(k + kvbase + (size_t)((kt) * 64 + srowi[1]) * DH + sgc[1] * 8,    \
            &Ks[bi][(wv * 2 + 1) * 512]);                                     \
    ASYNC16(vt + vtbase + (size_t)srowi[0] * SS + (kt) * 64 + sgc[0] * 8,     \
            &Vs[bi][(wv * 2 + 0) * 512]);                                     \
    ASYNC16(vt + vtbase + (size_t)srowi[1] * SS + (kt) * 64 + sgc[1] * 8,     \
            &Vs[bi][(wv * 2 + 1) * 512]);                                     \
  } while (0)

  const int Q0 = qp * 128;
  const int ew = 2 * qp + (wv >> 1);       // wave's edge tile (global index)
  const int qa = Q0 + wv * 32 + l31;

  short8 qf[4];
#pragma unroll
  for (int ks = 0; ks < 4; ++ks)
    qf[ks] = *(const short8*)(q + kvbase + (size_t)qa * DH + ks * 16 + hl * 8);

  floatx16 oacc[2] = {};
  float lsum = 0.f;

  STAGE(0, kb);
  __syncthreads();

  for (int g0 = kb; g0 < ke; ++g0) {
    const int cur = (g0 - kb) & 1;
    if (g0 + 1 < ke) STAGE((g0 - kb + 1) & 1, g0 + 1);

    if (g0 <= ew) {
      floatx16 st[2] = {};
      __builtin_amdgcn_s_setprio(1);
#pragma unroll
      for (int g = 0; g < 2; ++g) {
        const int row = g * 32 + l31;
        const int rx = row & 7;
#pragma unroll
        for (int ks = 0; ks < 4; ++ks) {
          const int uu = row * 8 + ((ks * 2 + hl) ^ rx);
          short8 kf = *(const short8*)&Ks[cur][uu * 8];
          st[g] = MFMA32(kf, qf[ks], st[g]);
        }
      }
      __builtin_amdgcn_s_setprio(0);

      float pv[2][16];
      if (g0 == ew) {
#pragma unroll
        for (int g = 0; g < 2; ++g)
#pragma unroll
          for (int r = 0; r < 16; ++r) {
            const int key = g0 * 64 + g * 32 + (r & 3) + 8 * (r >> 2) + 4 * hl;
            const float e = (key > qa)
                ? 0.f
                : exp2f(st[g][r] * 0.18033688011112042f - 11.541560327111707f);
            pv[g][r] = e;
            lsum += e;
          }
      } else {
#pragma unroll
        for (int g = 0; g < 2; ++g)
#pragma unroll
          for (int r = 0; r < 16; ++r) {
            const float e =
                exp2f(st[g][r] * 0.18033688011112042f - 11.541560327111707f);
            pv[g][r] = e;
            lsum += e;
          }
      }

      unsigned int W[2][4][2];
#pragma unroll
      for (int g = 0; g < 2; ++g)
#pragma unroll
        for (int bb = 0; bb < 4; ++bb)
#pragma unroll
          for (int w = 0; w < 2; ++w)
            asm("v_cvt_pk_bf16_f32 %0, %1, %2"
                : "=v"(W[g][bb][w])
                : "v"(pv[g][4 * bb + 2 * w]), "v"(pv[g][4 * bb + 2 * w + 1]));

#pragma unroll
      for (int ks = 0; ks < 4; ++ks) {
        const int g = ks >> 1, c2 = (ks & 1) * 2;
        const uint2v w0 = __builtin_amdgcn_permlane32_swap(
            W[g][c2][0], W[g][c2 + 1][0], false, false);
        const uint2v w1 = __builtin_amdgcn_permlane32_swap(
            W[g][c2][1], W[g][c2 + 1][1], false, false);
        union { unsigned int uu[4]; short8 s; } pa;
        pa.uu[0] = w0.x;
        pa.uu[1] = w1.x;
        pa.uu[2] = w0.y;
        pa.uu[3] = w1.y;
        __builtin_amdgcn_s_setprio(1);
#pragma unroll
        for (int dg = 0; dg < 2; ++dg) {
          const int row = dg * 32 + l31;
          const int uu = row * 8 + ((ks * 2 + hl) ^ (row & 7));
          short8 vf = *(const short8*)&Vs[cur][uu * 8];
          oacc[dg] = MFMA32(pa.s, vf, oacc[dg]);
        }
        __builtin_amdgcn_s_setprio(0);
      }
    }
    __syncthreads();
  }

  if (mode == 2) {
    const float rs = lsum + __shfl_xor(lsum, 32, 64);
    const float linv = 1.0f / rs;
#pragma unroll
    for (int r = 0; r < 16; ++r) {
      const int ql = (r & 3) + 8 * (r >> 2) + 4 * hl;
      const float li = __shfl(linv, ql, 64);
      const int qabs = Q0 + wv * 32 + ql;
#pragma unroll
      for (int dg = 0; dg < 2; ++dg) {
        const int d = dg * 32 + l31;
        ao[((size_t)(b * SS + qabs)) * DD + h * DH + d] = f2b(oacc[dg][r] * li);
      }
    }
  } else {
    // partial store: bf16 unnormalized pV sums + fp32 row-sum
    const int slab = ((qp - 8) * 2 + mode) * 64 + bh;
    const float rs = lsum + __shfl_xor(lsum, 32, 64);
    if (hl == 0) pL[slab * 128 + wv * 32 + l31] = rs;
#pragma unroll
    for (int r = 0; r < 16; ++r) {
      const int ql = (r & 3) + 8 * (r >> 2) + 4 * hl;
      const int row = wv * 32 + ql;
#pragma unroll
      for (int dg = 0; dg < 2; ++dg) {
        const int d = dg * 32 + l31;
        pO[((size_t)slab * 128 + row) * 64 + d] = f2b(oacc[dg][r]);
      }
    }
  }
#undef STAGE
}

// merge the two K-halves of each heavy q-tile: ao = (O0+O1)/(l0+l1)
__global__ __launch_bounds__(256) void attn_merge(
    const unsigned short* __restrict__ pO, const float* __restrict__ pL,
    unsigned short* __restrict__ ao) {
  const int flat = blockIdx.x * 256 + threadIdx.x;   // 0..131071
  const int row = flat >> 1, dh = (flat & 1) * 32;   // 65536 rows x 2 halves
  const int bh = row >> 10, p = (row >> 7) & 7, rl = row & 127;
  const int b = bh >> 4, h = bh & 15;
  const int qabs = 1024 + p * 128 + rl;              // qp = 8+p
  const int slab0 = (p * 2 + 0) * 64 + bh;
  const int slab1 = slab0 + 64;
  const float l = pL[slab0 * 128 + rl] + pL[slab1 * 128 + rl];
  const float inv = 1.0f / l;
  const unsigned short* o0 = &pO[((size_t)slab0 * 128 + rl) * 64 + dh];
  const unsigned short* o1 = &pO[((size_t)slab1 * 128 + rl) * 64 + dh];
  unsigned short* dst = &ao[((size_t)(b * SS + qabs)) * DD + h * DH + dh];
#pragma unroll
  for (int j = 0; j < 4; ++j) {
    union { short8 v; unsigned short u[8]; } a8, c8, pk;
    a8.v = *(const short8*)(o0 + 8 * j);
    c8.v = *(const short8*)(o1 + 8 * j);
#pragma unroll
    for (int e = 0; e < 8; ++e)
      pk.u[e] = f2b((b2f(a8.u[e]) + b2f(c8.u[e])) * inv);
    *(short8*)(dst + 8 * j) = pk.v;
  }
}

// ---------------------------------------------------------------------------
// o_gemm v2: out[8192,1024](fp32) = ab @ wo16^T (bf16).  BK=64 +
// XOR-swizzled LDS.
// ---------------------------------------------------------------------------
__global__ __launch_bounds__(256) void o_gemm(
    const unsigned short* __restrict__ a, const unsigned short* __restrict__ w16,
    float* __restrict__ out) {
  __shared__ __align__(16) unsigned short As[128 * 64];
  __shared__ __align__(16) unsigned short Bs[128 * 64];

  const int blk = blockIdx.x;          // 64 m x 8 n
  const int m0 = (blk >> 3) * 128;
  const int n0 = (blk & 7) * 128;

  const int tid = threadIdx.x;
  const int lane = tid & 63, wave = tid >> 6;
  const int wm = (wave >> 1) * 64, wn = (wave & 1) * 64;
  const int quad = lane >> 4, l15 = lane & 15;

  const int srw = lane >> 3;
  const int scw = ((lane & 7) ^ srw) * 8;
  const unsigned short* ag = a + (size_t)(m0 + wave * 32 + srw) * DD + scw;
  const unsigned short* bg = w16 + (size_t)(n0 + wave * 32 + srw) * DD + scw;
  unsigned short* al = &As[wave * 2048];
  unsigned short* bl = &Bs[wave * 2048];

  const int rx = l15 & 7;

  floatx4 acc[4][4] = {};

  for (int k0 = 0; k0 < DD; k0 += 64) {
    ASYNC16(ag + k0,           al);
    ASYNC16(ag + 8 * DD + k0,  al + 512);
    ASYNC16(ag + 16 * DD + k0, al + 1024);
    ASYNC16(ag + 24 * DD + k0, al + 1536);
    ASYNC16(bg + k0,           bl);
    ASYNC16(bg + 8 * DD + k0,  bl + 512);
    ASYNC16(bg + 16 * DD + k0, bl + 1024);
    ASYNC16(bg + 24 * DD + k0, bl + 1536);
    __syncthreads();
#pragma unroll
    for (int ks = 0; ks < 2; ++ks) {
      short8 af[4], bf[4];
#pragma unroll
      for (int mt = 0; mt < 4; ++mt)
        af[mt] = *(const short8*)&As[(wm + mt * 16 + l15) * 64 +
                                     (((ks * 4 + quad) ^ rx) * 8)];
#pragma unroll
      for (int nt = 0; nt < 4; ++nt)
        bf[nt] = *(const short8*)&Bs[(wn + nt * 16 + l15) * 64 +
                                     (((ks * 4 + quad) ^ rx) * 8)];
#pragma unroll
      for (int mt = 0; mt < 4; ++mt)
#pragma unroll
        for (int nt = 0; nt < 4; ++nt)
          acc[mt][nt] = MFMA16(af[mt], bf[nt], acc[mt][nt]);
    }
    __syncthreads();
  }

#pragma unroll
  for (int mt = 0; mt < 4; ++mt) {
#pragma unroll
    for (int nt = 0; nt < 4; ++nt) {
#pragma unroll
      for (int r = 0; r < 4; ++r) {
        const int row = m0 + wm + mt * 16 + quad * 4 + r;
        const int col = n0 + wn + nt * 16 + l15;
        out[(size_t)row * DD + col] = acc[mt][nt][r];
      }
    }
  }
}

extern "C" void kernel_launch(void* const* d_in, const int* in_sizes, int n_in,
                              void* d_out, int out_size, void* d_ws, size_t ws_size,
                              hipStream_t stream) {
  const float* x  = (const float*)d_in[0];
  const int* tpos = (const int*)d_in[1];
  const float* wq = (const float*)d_in[2];
  const float* wk = (const float*)d_in[3];
  const float* wv = (const float*)d_in[4];
  const float* wo = (const float*)d_in[5];

  const size_t N = (size_t)BB * SS * DD;           // 8,388,608
  unsigned short* qb  = (unsigned short*)d_out;    // bf16 q [B,H,S,DH]   (16.8 MB)
  unsigned short* w16 = qb + N;                    // bf16 q|k|v weights  (6.3 MB)
  float* costab = (float*)(w16 + (3u << 20));      // 2048x32 fp32 cos    (256 KB)
  float* sintab = costab + 65536;                  // 2048x32 fp32 sin    (256 KB)
  unsigned short* kb   = (unsigned short*)d_ws;    // bf16 k [B,H,S,DH]
  unsigned short* vb   = kb + N;                   // bf16 v^T [B,H,DH,S]
  unsigned short* ab   = vb + N;                   // bf16 attn [B,S,D]
  unsigned short* wo16 = ab + N;                   // bf16 wo
  unsigned short* x16  = ab;                       // alias: dead before attn writes ab
  float* out = (float*)d_out;

  // split-K attention partials (bf16 pO + fp32 pL), after wo16.
  const size_t base = (3 * N + (1u << 20)) * sizeof(unsigned short); // 52.43 MB
  const size_t WS_NEED = base + 8388608ull * sizeof(unsigned short)
                              + 131072ull * sizeof(float);

  cvt_all<<<6400, 256, 0, stream>>>(x, wq, wk, wv, wo, x16, w16, wo16,
                                    costab, sintab);
  qkv_gemm<<<64 * 24, 256, 0, stream>>>(x16, w16, tpos, costab, sintab,
                                        qb, kb, vb);
  if (ws_size >= WS_NEED) {
    unsigned short* pO = (unsigned short*)((char*)d_ws + base);
    float* pL = (float*)(pO + 8388608);
    attn_split<<<24 * 64, 256, 0, stream>>>(qb, kb, vb, ab, pO, pL);
    attn_merge<<<512, 256, 0, stream>>>(pO, pL, ab);
  } else {
    attn_flash<<<16 * 64, 256, 0, stream>>>(qb, kb, vb, ab);
  }
  o_gemm<<<64 * 8, 256, 0, stream>>>(ab, wo16, out);
}